// Round 15
// baseline (433.142 us; speedup 1.0000x reference)
//
#include <hip/hip_runtime.h>
#include <hip/hip_bf16.h>

// PartitionedNormalization: per-domain BN stats (training mode) + affine.
// out[B][128] f32 = (gg+dg[s])*(x-mean[s])*rsqrt(var[s]+eps) + (gb+db[s])
//
// R15 (single variable vs R14): pass 1 accumulates via LDS ds_add_f32
// atomics into ONE 8KB block-shared region (was: 8 half-wave-private
// regions, 64KB, 2 blocks/CU). Fire-and-forget atomics remove the
// read-back lgkmcnt chain; 8KB LDS lifts occupancy to the wave cap.
// Bank layout: lane l -> word s*128+{l,64+l} -> bank l%32, 2-way = free.

#define DIM 128
#define NDOM 8
#define PENT (NDOM + 2 * NDOM * DIM)  // 8 counts + 1024 sums + 1024 sqsums = 2056
#define EPSV 1e-3f

// ---------------- pass 1: block-shared LDS atomic accumulation ----------------
__global__ __launch_bounds__(256) void pn_reduce(const float* __restrict__ x,
                                                 const int* __restrict__ seg,
                                                 float* __restrict__ partials,
                                                 int rowsPerBlock) {
  __shared__ float acc[2 * NDOM * DIM];  // sums[1024] | sqs[1024] = 8KB
  __shared__ float lcnt[NDOM];
  const int tid = threadIdx.x;
  const int w = tid >> 6;  // wave 0..3
  const int l = tid & 63;  // lane

  for (int i = tid; i < 2 * NDOM * DIM; i += 256) acc[i] = 0.f;
  if (tid < NDOM) lcnt[tid] = 0.f;
  __syncthreads();

  const int rowsPerWave = rowsPerBlock >> 2;  // 32 at NB=2048
  const int row0 = blockIdx.x * rowsPerBlock + w * rowsPerWave;

#define UPD(S, A, B)                                      \
  {                                                       \
    atomicAdd(&acc[(S) * DIM + l], (A));                  \
    atomicAdd(&acc[(S) * DIM + 64 + l], (B));             \
    atomicAdd(&acc[NDOM * DIM + (S) * DIM + l], (A) * (A));      \
    atomicAdd(&acc[NDOM * DIM + (S) * DIM + 64 + l], (B) * (B)); \
  }
  for (int it = 0; it < rowsPerWave; it += 4) {
    const int r = row0 + it;
    const int4 sg = *(const int4*)(seg + r);  // 4 rows' domains
    // 4 rows x 2 coalesced dword columns per lane (cols l and 64+l)
    const float a0 = x[(size_t)(r + 0) * DIM + l];
    const float b0 = x[(size_t)(r + 0) * DIM + 64 + l];
    const float a1 = x[(size_t)(r + 1) * DIM + l];
    const float b1 = x[(size_t)(r + 1) * DIM + 64 + l];
    const float a2 = x[(size_t)(r + 2) * DIM + l];
    const float b2 = x[(size_t)(r + 2) * DIM + 64 + l];
    const float a3 = x[(size_t)(r + 3) * DIM + l];
    const float b3 = x[(size_t)(r + 3) * DIM + 64 + l];
    UPD(sg.x, a0, b0)
    UPD(sg.y, a1, b1)
    UPD(sg.z, a2, b2)
    UPD(sg.w, a3, b3)
  }
#undef UPD
  __syncthreads();

  // counts: one-time histogram of this block's rows (seg re-read is L2-hit)
  for (int i = tid; i < rowsPerBlock; i += 256)
    atomicAdd(&lcnt[seg[blockIdx.x * rowsPerBlock + i]], 1.f);
  __syncthreads();

  // flush: counts | sums | sqs (coalesced)
  float* outp = partials + (size_t)blockIdx.x * PENT;
  if (tid < NDOM) outp[tid] = lcnt[tid];
  for (int i = tid; i < 2 * NDOM * DIM; i += 256) outp[NDOM + i] = acc[i];
}

// ---------------- pass 2a: reduce NB partial rows -> 64 ----------------
__global__ __launch_bounds__(256) void pn_reduce2(const float* __restrict__ partials,
                                                  float* __restrict__ partials2,
                                                  int NB) {
  const int b = blockIdx.x;  // 0..63
  const int per = NB >> 6;
  const int b0 = b * per;
  const int tid = threadIdx.x;
  float acc[9];
#pragma unroll
  for (int i = 0; i < 9; ++i) acc[i] = 0.f;
  for (int j = b0; j < b0 + per; ++j) {
    const float* p = partials + (size_t)j * PENT;
#pragma unroll
    for (int i = 0; i < 9; ++i) {
      const int e = tid + i * 256;
      if (e < PENT) acc[i] += p[e];
    }
  }
  float* o = partials2 + (size_t)b * PENT;
#pragma unroll
  for (int i = 0; i < 9; ++i) {
    const int e = tid + i * 256;
    if (e < PENT) o[e] = acc[i];
  }
}

// ---------------- pass 2b: final reduce + scale/shift table (4 blocks) ----------------
__global__ __launch_bounds__(256) void pn_finalize(const float* __restrict__ partials2,
                                                   const float* __restrict__ gg,
                                                   const float* __restrict__ gb,
                                                   const float* __restrict__ dg,
                                                   const float* __restrict__ db,
                                                   float* __restrict__ stats) {
  const int t = blockIdx.x * 256 + threadIdx.x;  // (k = t>>7, d = t&127)
  const int k = t >> 7;
  const int d = t & (DIM - 1);
  float c = 0.f, s = 0.f, q = 0.f;
  for (int j = 0; j < 64; ++j) {
    const float* p = partials2 + (size_t)j * PENT;
    c += p[k];
    s += p[NDOM + t];
    q += p[NDOM + NDOM * DIM + t];
  }
  const float n = fmaxf(c, 1.f);
  const float mean = s / n;
  const float var = fmaxf(q / n - mean * mean, 0.f);
  const float rstd = rsqrtf(var + EPSV);
  const float scale = (gg[d] + dg[t]) * rstd;  // dg[k*128+d] == dg[t]
  const float shift = (gb[d] + db[t]) - scale * mean;
  stats[t] = scale;
  stats[NDOM * DIM + t] = shift;
}

// ---------------- pass 3: normalize (one-shot, 1 float4/thread) ----------------
__global__ __launch_bounds__(256) void pn_apply(const float* __restrict__ x,
                                                const int* __restrict__ seg,
                                                const float* __restrict__ stats,
                                                float* __restrict__ out) {
  const int g = blockIdx.x * 256 + threadIdx.x;  // float4 index
  const int row = g >> 5;                        // 32 float4 per row
  const int c4 = g & 31;
  const int s = seg[row];
  const float4 xv = ((const float4*)x)[g];
  const float4 a = ((const float4*)(stats + s * DIM))[c4];
  const float4 b = ((const float4*)(stats + NDOM * DIM + s * DIM))[c4];
  float4 o;
  o.x = fmaf(xv.x, a.x, b.x);
  o.y = fmaf(xv.y, a.y, b.y);
  o.z = fmaf(xv.z, a.z, b.z);
  o.w = fmaf(xv.w, a.w, b.w);
  ((float4*)out)[g] = o;
}

extern "C" void kernel_launch(void* const* d_in, const int* in_sizes, int n_in,
                              void* d_out, int out_size, void* d_ws, size_t ws_size,
                              hipStream_t stream) {
  const float* x = (const float*)d_in[0];
  const float* gg = (const float*)d_in[1];
  const float* gb = (const float*)d_in[2];
  const float* dg = (const float*)d_in[3];
  const float* db = (const float*)d_in[4];
  const int* seg = (const int*)d_in[5];
  float* out = (float*)d_out;
  const int B = in_sizes[5];  // 262144

  // workspace: partials[NB][PENT] | partials2[64][PENT] | stats[2048]
  const int NB = 2048;  // 8 blocks/CU (wave cap), one co-resident round
  float* partials = (float*)d_ws;
  float* partials2 = partials + (size_t)NB * PENT;
  float* stats = partials2 + (size_t)64 * PENT;

  const int rpb = B / NB;  // 128 rows/block; 32 contiguous rows/wave

  pn_reduce<<<NB, 256, 0, stream>>>(x, seg, partials, rpb);
  pn_reduce2<<<64, 256, 0, stream>>>(partials, partials2, NB);
  pn_finalize<<<4, 256, 0, stream>>>(partials2, gg, gb, dg, db, stats);

  const int nblk = (B * (DIM / 4)) / 256;  // 32768
  pn_apply<<<nblk, 256, 0, stream>>>(x, seg, stats, out);
}

// Round 16
// 138.943 us; speedup vs baseline: 3.1174x; 3.1174x over previous
//
#include <hip/hip_runtime.h>
#include <hip/hip_bf16.h>

// PartitionedNormalization: per-domain BN stats (training mode) + affine.
// out[B][128] f32 = (gg+dg[s])*(x-mean[s])*rsqrt(var[s]+eps) + (gb+db[s])
//
// R16: revert R15 (LDS atomics in hot loop = 339us, same as R1 — twice-
// measured lesson). New pass 1: wave-per-row + wave-uniform switch(seg)
// into NAMED register accumulators (only the matching domain's 4 fmas run);
// zero DS ops in the hot loop; one-time LDS-atomic flush per block.

#define DIM 128
#define NDOM 8
#define PENT (NDOM + 2 * NDOM * DIM)  // 8 counts + 1024 sums + 1024 sqsums = 2056
#define EPSV 1e-3f

// ---------------- pass 1: register-switch accumulation ----------------
__global__ __launch_bounds__(256) void pn_reduce(const float2* __restrict__ x2,
                                                 const int* __restrict__ seg,
                                                 float* __restrict__ partials,
                                                 int rowsPerBlock) {
  __shared__ float acc[2 * NDOM * DIM];  // sums[1024] | sqs[1024] = 8KB
  __shared__ float lcnt[NDOM];
  const int tid = threadIdx.x;
  const int w = tid >> 6;  // wave 0..3
  const int l = tid & 63;  // lane; covers cols 2l, 2l+1

  for (int i = tid; i < 2 * NDOM * DIM; i += 256) acc[i] = 0.f;
  if (tid < NDOM) lcnt[tid] = 0.f;
  __syncthreads();

  const int rowsPerWave = rowsPerBlock >> 2;  // 64 at NB=1024
  const int row0 = blockIdx.x * rowsPerBlock + w * rowsPerWave;

  // 8 domains x (sum.x,sum.y,sq.x,sq.y) as NAMED scalars (rule #20).
#define DECL(K) float s##K##x = 0.f, s##K##y = 0.f, q##K##x = 0.f, q##K##y = 0.f;
  DECL(0) DECL(1) DECL(2) DECL(3) DECL(4) DECL(5) DECL(6) DECL(7)

  // Wave-uniform switch; asm volatile("") per case blocks if-conversion
  // (R5 lesson: linearized cndmask chains over all 8 domains = 17 op/elem).
#define CASE(K, V)                                          \
  case K:                                                   \
    s##K##x += (V).x;                                       \
    s##K##y += (V).y;                                       \
    q##K##x = fmaf((V).x, (V).x, q##K##x);                  \
    q##K##y = fmaf((V).y, (V).y, q##K##y);                  \
    asm volatile("");                                       \
    break;
#define SW(S, V)                                            \
  switch (S) {                                              \
    CASE(0, V) CASE(1, V) CASE(2, V) CASE(3, V)             \
    CASE(4, V) CASE(5, V) CASE(6, V) CASE(7, V)             \
  }

  for (int it = 0; it < rowsPerWave; it += 4) {
    const int r = row0 + it;
    const int4 sg = *(const int4*)(seg + r);  // 4 rows' domains (uniform/wave)
    const float2 v0 = x2[(size_t)(r + 0) * 64 + l];
    const float2 v1 = x2[(size_t)(r + 1) * 64 + l];
    const float2 v2 = x2[(size_t)(r + 2) * 64 + l];
    const float2 v3 = x2[(size_t)(r + 3) * 64 + l];
    SW(sg.x, v0)
    SW(sg.y, v1)
    SW(sg.z, v2)
    SW(sg.w, v3)
  }
#undef SW
#undef CASE
#undef DECL

  // one-time flush: 32 ds atomics/thread (outside hot loop)
#define FL(K)                                                   \
  {                                                             \
    atomicAdd(&acc[K * DIM + 2 * l], s##K##x);                  \
    atomicAdd(&acc[K * DIM + 2 * l + 1], s##K##y);              \
    atomicAdd(&acc[NDOM * DIM + K * DIM + 2 * l], q##K##x);     \
    atomicAdd(&acc[NDOM * DIM + K * DIM + 2 * l + 1], q##K##y); \
  }
  FL(0) FL(1) FL(2) FL(3) FL(4) FL(5) FL(6) FL(7)
#undef FL
  __syncthreads();

  // counts: one-time histogram (seg re-read is L2-hit)
  for (int i = tid; i < rowsPerBlock; i += 256)
    atomicAdd(&lcnt[seg[blockIdx.x * rowsPerBlock + i]], 1.f);
  __syncthreads();

  float* outp = partials + (size_t)blockIdx.x * PENT;
  if (tid < NDOM) outp[tid] = lcnt[tid];
  for (int i = tid; i < 2 * NDOM * DIM; i += 256) outp[NDOM + i] = acc[i];
}

// ---------------- pass 2a: reduce NB partial rows -> 64 ----------------
__global__ __launch_bounds__(256) void pn_reduce2(const float* __restrict__ partials,
                                                  float* __restrict__ partials2,
                                                  int NB) {
  const int b = blockIdx.x;  // 0..63
  const int per = NB >> 6;
  const int b0 = b * per;
  const int tid = threadIdx.x;
  float acc[9];
#pragma unroll
  for (int i = 0; i < 9; ++i) acc[i] = 0.f;
  for (int j = b0; j < b0 + per; ++j) {
    const float* p = partials + (size_t)j * PENT;
#pragma unroll
    for (int i = 0; i < 9; ++i) {
      const int e = tid + i * 256;
      if (e < PENT) acc[i] += p[e];
    }
  }
  float* o = partials2 + (size_t)b * PENT;
#pragma unroll
  for (int i = 0; i < 9; ++i) {
    const int e = tid + i * 256;
    if (e < PENT) o[e] = acc[i];
  }
}

// ---------------- pass 2b: final reduce + scale/shift table (4 blocks) ----------------
__global__ __launch_bounds__(256) void pn_finalize(const float* __restrict__ partials2,
                                                   const float* __restrict__ gg,
                                                   const float* __restrict__ gb,
                                                   const float* __restrict__ dg,
                                                   const float* __restrict__ db,
                                                   float* __restrict__ stats) {
  const int t = blockIdx.x * 256 + threadIdx.x;  // (k = t>>7, d = t&127)
  const int k = t >> 7;
  const int d = t & (DIM - 1);
  float c = 0.f, s = 0.f, q = 0.f;
  for (int j = 0; j < 64; ++j) {
    const float* p = partials2 + (size_t)j * PENT;
    c += p[k];
    s += p[NDOM + t];
    q += p[NDOM + NDOM * DIM + t];
  }
  const float n = fmaxf(c, 1.f);
  const float mean = s / n;
  const float var = fmaxf(q / n - mean * mean, 0.f);
  const float rstd = rsqrtf(var + EPSV);
  const float scale = (gg[d] + dg[t]) * rstd;  // dg[k*128+d] == dg[t]
  const float shift = (gb[d] + db[t]) - scale * mean;
  stats[t] = scale;
  stats[NDOM * DIM + t] = shift;
}

// ---------------- pass 3: normalize (one-shot, 1 float4/thread) ----------------
__global__ __launch_bounds__(256) void pn_apply(const float* __restrict__ x,
                                                const int* __restrict__ seg,
                                                const float* __restrict__ stats,
                                                float* __restrict__ out) {
  const int g = blockIdx.x * 256 + threadIdx.x;  // float4 index
  const int row = g >> 5;                        // 32 float4 per row
  const int c4 = g & 31;
  const int s = seg[row];
  const float4 xv = ((const float4*)x)[g];
  const float4 a = ((const float4*)(stats + s * DIM))[c4];
  const float4 b = ((const float4*)(stats + NDOM * DIM + s * DIM))[c4];
  float4 o;
  o.x = fmaf(xv.x, a.x, b.x);
  o.y = fmaf(xv.y, a.y, b.y);
  o.z = fmaf(xv.z, a.z, b.z);
  o.w = fmaf(xv.w, a.w, b.w);
  ((float4*)out)[g] = o;
}

extern "C" void kernel_launch(void* const* d_in, const int* in_sizes, int n_in,
                              void* d_out, int out_size, void* d_ws, size_t ws_size,
                              hipStream_t stream) {
  const float* x = (const float*)d_in[0];
  const float* gg = (const float*)d_in[1];
  const float* gb = (const float*)d_in[2];
  const float* dg = (const float*)d_in[3];
  const float* db = (const float*)d_in[4];
  const int* seg = (const int*)d_in[5];
  float* out = (float*)d_out;
  const int B = in_sizes[5];  // 262144

  // workspace: partials[NB][PENT] | partials2[64][PENT] | stats[2048]
  const int NB = 1024;  // 4 blocks/CU (8.4KB LDS -> VGPR-bound occupancy)
  float* partials = (float*)d_ws;
  float* partials2 = partials + (size_t)NB * PENT;
  float* stats = partials2 + (size_t)64 * PENT;

  const int rpb = B / NB;  // 256 rows/block; 64 rows/wave

  pn_reduce<<<NB, 256, 0, stream>>>((const float2*)x, seg, partials, rpb);
  pn_reduce2<<<64, 256, 0, stream>>>(partials, partials2, NB);
  pn_finalize<<<4, 256, 0, stream>>>(partials2, gg, gb, dg, db, stats);

  const int nblk = (B * (DIM / 4)) / 256;  // 32768
  pn_apply<<<nblk, 256, 0, stream>>>(x, seg, stats, out);
}

// Round 18
// 90.883 us; speedup vs baseline: 4.7659x; 1.5288x over previous
//
#include <hip/hip_runtime.h>
#include <hip/hip_bf16.h>

// PartitionedNormalization: per-domain BN stats (training mode) + affine.
// out[B][128] f32 = (gg+dg[s])*(x-mean[s])*rsqrt(var[s]+eps) + (gb+db[s])
//
// R18 = R17 resubmitted (container died before benching). R14 best=91.75us.
// Single change vs R14: pass-1 inner loop unrolled 2x (8 global loads in
// flight per wave before the 8 RMW pairs; was 4).

#define DIM 128
#define NDOM 8
#define PENT (NDOM + 2 * NDOM * DIM)  // 8 counts + 1024 sums + 1024 sqsums = 2056
#define EPSV 1e-3f
#define WREG 2048  // per half-wave region (floats): sums[8][128] | sqs[8][128]

// ---------------- pass 1: half-wave-private LDS accumulation ----------------
__global__ __launch_bounds__(256) void pn_reduce(const float4* __restrict__ x4,
                                                 const int* __restrict__ seg,
                                                 float* __restrict__ partials,
                                                 int rowsPerBlock) {
  __shared__ float acc[8 * WREG];  // 64 KB -> 2 blocks/CU
  __shared__ float lcnt[NDOM];
  const int tid = threadIdx.x;
  const int w = tid >> 6;  // wave 0..3
  const int l = tid & 63;
  const int h = l >> 5;    // half-wave: row parity
  const int g = l & 31;    // float4 col group
  float* reg = acc + (w * 2 + h) * WREG;  // half-wave private

  for (int i = tid; i < 2 * WREG; i += 256)
    ((float4*)acc)[i] = make_float4(0.f, 0.f, 0.f, 0.f);
  if (tid < NDOM) lcnt[tid] = 0.f;
  __syncthreads();

  const int rowsPerWave = rowsPerBlock >> 2;  // 128 at NB=512
  const int row0 = blockIdx.x * rowsPerBlock + w * rowsPerWave;

#define RMW(S, V)                                    \
  {                                                  \
    float* bs = reg + (S) * 128 + g * 4;             \
    float* bq = bs + NDOM * DIM;                     \
    float4 os = *(float4*)bs;                        \
    float4 oq = *(float4*)bq;                        \
    os.x += (V).x;                                   \
    os.y += (V).y;                                   \
    os.z += (V).z;                                   \
    os.w += (V).w;                                   \
    oq.x = fmaf((V).x, (V).x, oq.x);                 \
    oq.y = fmaf((V).y, (V).y, oq.y);                 \
    oq.z = fmaf((V).z, (V).z, oq.z);                 \
    oq.w = fmaf((V).w, (V).w, oq.w);                 \
    *(float4*)bs = os;                               \
    *(float4*)bq = oq;                               \
  }
  for (int it = 0; it < rowsPerWave; it += 16) {
    const int r = row0 + it;
    const int4 sgA = *(const int4*)(seg + r);       // rows r..r+3
    const int4 sgB = *(const int4*)(seg + r + 4);   // rows r+4..r+7
    const int4 sgC = *(const int4*)(seg + r + 8);   // rows r+8..r+11
    const int4 sgD = *(const int4*)(seg + r + 12);  // rows r+12..r+15
    // 8 independent 1KB loads in flight before any RMW
    const float4 v0 = x4[(size_t)(r + 0 + h) * 32 + g];
    const float4 v1 = x4[(size_t)(r + 2 + h) * 32 + g];
    const float4 v2 = x4[(size_t)(r + 4 + h) * 32 + g];
    const float4 v3 = x4[(size_t)(r + 6 + h) * 32 + g];
    const float4 v4 = x4[(size_t)(r + 8 + h) * 32 + g];
    const float4 v5 = x4[(size_t)(r + 10 + h) * 32 + g];
    const float4 v6 = x4[(size_t)(r + 12 + h) * 32 + g];
    const float4 v7 = x4[(size_t)(r + 14 + h) * 32 + g];
    const int s0 = h ? sgA.y : sgA.x;
    const int s1 = h ? sgA.w : sgA.z;
    const int s2 = h ? sgB.y : sgB.x;
    const int s3 = h ? sgB.w : sgB.z;
    const int s4 = h ? sgC.y : sgC.x;
    const int s5 = h ? sgC.w : sgC.z;
    const int s6 = h ? sgD.y : sgD.x;
    const int s7 = h ? sgD.w : sgD.z;
    RMW(s0, v0)
    RMW(s1, v1)
    RMW(s2, v2)
    RMW(s3, v3)
    RMW(s4, v4)
    RMW(s5, v5)
    RMW(s6, v6)
    RMW(s7, v7)
  }
#undef RMW
  __syncthreads();

  for (int i = tid; i < rowsPerBlock; i += 256)
    atomicAdd(&lcnt[seg[blockIdx.x * rowsPerBlock + i]], 1.f);
  __syncthreads();

  float* outp = partials + (size_t)blockIdx.x * PENT;
  if (tid < NDOM) outp[tid] = lcnt[tid];
  for (int i = tid; i < 2 * NDOM * DIM; i += 256) {
    float v = 0.f;
#pragma unroll
    for (int rr = 0; rr < 8; ++rr) v += acc[rr * WREG + i];
    outp[NDOM + i] = v;
  }
}

// ---------------- pass 2a: reduce NB partial rows -> 64 ----------------
__global__ __launch_bounds__(256) void pn_reduce2(const float* __restrict__ partials,
                                                  float* __restrict__ partials2,
                                                  int NB) {
  const int b = blockIdx.x;  // 0..63
  const int per = NB >> 6;
  const int b0 = b * per;
  const int tid = threadIdx.x;
  float acc[9];
#pragma unroll
  for (int i = 0; i < 9; ++i) acc[i] = 0.f;
  for (int j = b0; j < b0 + per; ++j) {
    const float* p = partials + (size_t)j * PENT;
#pragma unroll
    for (int i = 0; i < 9; ++i) {
      const int e = tid + i * 256;
      if (e < PENT) acc[i] += p[e];
    }
  }
  float* o = partials2 + (size_t)b * PENT;
#pragma unroll
  for (int i = 0; i < 9; ++i) {
    const int e = tid + i * 256;
    if (e < PENT) o[e] = acc[i];
  }
}

// ---------------- pass 2b: final reduce + scale/shift table (4 blocks) ----------------
__global__ __launch_bounds__(256) void pn_finalize(const float* __restrict__ partials2,
                                                   const float* __restrict__ gg,
                                                   const float* __restrict__ gb,
                                                   const float* __restrict__ dg,
                                                   const float* __restrict__ db,
                                                   float* __restrict__ stats) {
  const int t = blockIdx.x * 256 + threadIdx.x;  // (k = t>>7, d = t&127)
  const int k = t >> 7;
  const int d = t & (DIM - 1);
  float c = 0.f, s = 0.f, q = 0.f;
  for (int j = 0; j < 64; ++j) {
    const float* p = partials2 + (size_t)j * PENT;
    c += p[k];
    s += p[NDOM + t];
    q += p[NDOM + NDOM * DIM + t];
  }
  const float n = fmaxf(c, 1.f);
  const float mean = s / n;
  const float var = fmaxf(q / n - mean * mean, 0.f);
  const float rstd = rsqrtf(var + EPSV);
  const float scale = (gg[d] + dg[t]) * rstd;  // dg[k*128+d] == dg[t]
  const float shift = (gb[d] + db[t]) - scale * mean;
  stats[t] = scale;
  stats[NDOM * DIM + t] = shift;
}

// ---------------- pass 3: normalize (one-shot, 1 float4/thread) ----------------
__global__ __launch_bounds__(256) void pn_apply(const float* __restrict__ x,
                                                const int* __restrict__ seg,
                                                const float* __restrict__ stats,
                                                float* __restrict__ out) {
  const int g = blockIdx.x * 256 + threadIdx.x;  // float4 index
  const int row = g >> 5;                        // 32 float4 per row
  const int c4 = g & 31;
  const int s = seg[row];
  const float4 xv = ((const float4*)x)[g];
  const float4 a = ((const float4*)(stats + s * DIM))[c4];
  const float4 b = ((const float4*)(stats + NDOM * DIM + s * DIM))[c4];
  float4 o;
  o.x = fmaf(xv.x, a.x, b.x);
  o.y = fmaf(xv.y, a.y, b.y);
  o.z = fmaf(xv.z, a.z, b.z);
  o.w = fmaf(xv.w, a.w, b.w);
  ((float4*)out)[g] = o;
}

extern "C" void kernel_launch(void* const* d_in, const int* in_sizes, int n_in,
                              void* d_out, int out_size, void* d_ws, size_t ws_size,
                              hipStream_t stream) {
  const float* x = (const float*)d_in[0];
  const float* gg = (const float*)d_in[1];
  const float* gb = (const float*)d_in[2];
  const float* dg = (const float*)d_in[3];
  const float* db = (const float*)d_in[4];
  const int* seg = (const int*)d_in[5];
  float* out = (float*)d_out;
  const int B = in_sizes[5];  // 262144

  // workspace: partials[NB][PENT] | partials2[64][PENT] | stats[2048]
  const int NB = 512;  // 2 blocks/CU, one co-resident round
  float* partials = (float*)d_ws;
  float* partials2 = partials + (size_t)NB * PENT;
  float* stats = partials2 + (size_t)64 * PENT;

  const int rpb = B / NB;  // 512 rows/block; 128 contiguous rows/wave

  pn_reduce<<<NB, 256, 0, stream>>>((const float4*)x, seg, partials, rpb);
  pn_reduce2<<<64, 256, 0, stream>>>(partials, partials2, NB);
  pn_finalize<<<4, 256, 0, stream>>>(partials2, gg, gb, dg, db, stats);

  const int nblk = (B * (DIM / 4)) / 256;  // 32768
  pn_apply<<<nblk, 256, 0, stream>>>(x, seg, stats, out);
}